// Round 2
// baseline (6465.603 us; speedup 1.0000x reference)
//
#include <hip/hip_runtime.h>

#define NNODE 1000
#define NBATCH 8
#define SEQL 12
#define NHEAD 8
#define DHEAD 16
#define HID 128
#define NEDGE 16000
#define NROWS (NBATCH*NNODE)   // 8000
#define RPB 16                 // rows per block
#define NBLK (NROWS/RPB)       // 500
#define DT 0.25f

__device__ __forceinline__ float lrelu(float x){ return fmaxf(x, 0.2f*x); }

// copy a 128x128 fp32 matrix from global into LDS (row-major)
__device__ __forceinline__ void load_W(float* Wl, const float* g, int tid){
  #pragma unroll
  for (int c=0;c<16;++c){
    int e = (c*256 + tid)*4;
    *reinterpret_cast<float4*>(Wl + e) = *reinterpret_cast<const float4*>(g + e);
  }
}

// C[row][j] = sum_k yt[row][k] * Wl[k][j]; thread covers features fg*4..fg*4+3
// for rows rs and rs+8 of the 16-row tile.
__device__ __forceinline__ void gemm128(const float* Wl, const float* yt, int fg, int rs,
                                        float o0[4], float o1[4]){
  float a0[4]={0.f,0.f,0.f,0.f}, a1[4]={0.f,0.f,0.f,0.f};
  #pragma unroll 4
  for (int k=0;k<HID;k+=4){
    float4 ya = *reinterpret_cast<const float4*>(yt + rs*HID + k);
    float4 yb = *reinterpret_cast<const float4*>(yt + (rs+8)*HID + k);
    #pragma unroll
    for (int kk=0;kk<4;++kk){
      const float* wr = Wl + (k+kk)*HID + fg*4;
      float av = (&ya.x)[kk];
      float bv = (&yb.x)[kk];
      #pragma unroll
      for (int i=0;i<4;++i){
        float w = wr[i];
        a0[i] = fmaf(w, av, a0[i]);
        a1[i] = fmaf(w, bv, a1[i]);
      }
    }
  }
  #pragma unroll
  for (int i=0;i<4;++i){ o0[i]=a0[i]; o1[i]=a1[i]; }
}

// Build CSR (edges sorted by dst) from src/dst. Single block.
__global__ void csr_kernel(const int* __restrict__ src, const int* __restrict__ dst,
                           int* __restrict__ row_start, int* __restrict__ edge_src){
  __shared__ int cnt[1024];
  __shared__ int scanb[1024];
  __shared__ int cur[1024];
  int tid = threadIdx.x;
  cnt[tid] = 0;
  __syncthreads();
  for (int e = tid; e < NEDGE; e += 1024) atomicAdd(&cnt[dst[e]], 1);
  __syncthreads();
  int v = cnt[tid];
  scanb[tid] = v;
  __syncthreads();
  for (int off=1; off<1024; off<<=1){
    int t = (tid >= off) ? scanb[tid-off] : 0;
    __syncthreads();
    scanb[tid] += t;
    __syncthreads();
  }
  int incl = scanb[tid];
  if (tid < NNODE){ cur[tid] = incl - v; row_start[tid+1] = incl; }
  if (tid == 0) row_start[0] = 0;
  __syncthreads();
  for (int e = tid; e < NEDGE; e += 1024){
    int d = dst[e];
    int pos = atomicAdd(&cur[d], 1);
    edge_src[pos] = src[e];
  }
}

// mode: 0=init(y0 from inputs, GEMM only), 1=RK4 k1, 2=k2, 3=k3,
//       4=k4 mid-interval, 5=k4 end-of-interval (GRU if seq_idx>0, then LN)
__global__ void __launch_bounds__(256, 2) fused_eval(
    const float* __restrict__ h_rd, const float* __restrict__ el_rd, const float* __restrict__ er_rd,
    float* __restrict__ h_wr, float* __restrict__ el_wr, float* __restrict__ er_wr,
    float* __restrict__ y_base, float* __restrict__ y_acc,
    const int* __restrict__ row_start, const int* __restrict__ edge_src,
    const float* __restrict__ w_gat, const float* __restrict__ a_l, const float* __restrict__ a_r,
    const float* __restrict__ inputs, const float* __restrict__ w_in, const float* __restrict__ b_in,
    const float* __restrict__ w_Wm, const float* __restrict__ b_Wv,
    const float* __restrict__ w_Um, const float* __restrict__ b_Uv,
    int mode, int seq_idx, int write_h)
{
  __shared__ float Wl[HID*HID];   // 64 KB
  __shared__ float yt[RPB*HID];   // 8 KB
  const int tid = threadIdx.x;
  const int row0 = blockIdx.x * RPB;
  // layout A: 16 threads per row
  const int rA = tid >> 4, tA = tid & 15;
  const int rowA = row0 + rA;
  const int bA = rowA / NNODE;
  const int nA = rowA - bA * NNODE;

  if (mode == 0) {
    // y0 = inputs[:,0] @ w_in + b_in
    float x0 = inputs[((bA*SEQL + 0)*NNODE + nA)*2 + 0];
    float x1 = inputs[((bA*SEQL + 0)*NNODE + nA)*2 + 1];
    float v[8];
    #pragma unroll
    for (int i=0;i<8;++i){
      int f = tA*8 + i;
      v[i] = x0*w_in[f] + x1*w_in[HID+f] + b_in[f];
      yt[rA*HID + f] = v[i];
    }
    *reinterpret_cast<float4*>(y_base + rowA*HID + tA*8)     = make_float4(v[0],v[1],v[2],v[3]);
    *reinterpret_cast<float4*>(y_base + rowA*HID + tA*8 + 4) = make_float4(v[4],v[5],v[6],v[7]);
  } else {
    // ---- Phase A: GAT edge-softmax aggregation for this row ----
    // Values are bounded (|el+er| << 30): single-pass softmax without
    // max-shift is identical to the reference within fp noise.
    const int s0 = row_start[nA], s1 = row_start[nA+1];
    const int hd = tA >> 1;           // features 8tA..8tA+7 all in head tA/2
    const float erh = er_rd[rowA*NHEAD + hd];
    float sum = 0.f;
    float acc[8] = {0.f,0.f,0.f,0.f,0.f,0.f,0.f,0.f};
    for (int e = s0; e < s1; ++e){
      int s = edge_src[e];
      int sb = bA*NNODE + s;
      float x = el_rd[sb*NHEAD + hd] + erh;
      float w = __expf(fminf(fmaxf(x, 0.2f*x), 30.f));
      sum += w;
      const float* hp = h_rd + sb*HID + tA*8;
      float4 h0 = *reinterpret_cast<const float4*>(hp);
      float4 h1 = *reinterpret_cast<const float4*>(hp + 4);
      acc[0] = fmaf(w, h0.x, acc[0]); acc[1] = fmaf(w, h0.y, acc[1]);
      acc[2] = fmaf(w, h0.z, acc[2]); acc[3] = fmaf(w, h0.w, acc[3]);
      acc[4] = fmaf(w, h1.x, acc[4]); acc[5] = fmaf(w, h1.y, acc[5]);
      acc[6] = fmaf(w, h1.z, acc[6]); acc[7] = fmaf(w, h1.w, acc[7]);
    }
    float inv = 1.0f / (sum + 1e-16f);
    #pragma unroll
    for (int i=0;i<8;++i) acc[i] *= inv;   // acc = k_j features 8tA..8tA+7

    // ---- Phase B: RK4 state update (node-local) ----
    const float* ybp = y_base + rowA*HID + tA*8;
    float4 yb0 = *reinterpret_cast<const float4*>(ybp);
    float4 yb1 = *reinterpret_cast<const float4*>(ybp + 4);
    float yb8[8] = {yb0.x,yb0.y,yb0.z,yb0.w,yb1.x,yb1.y,yb1.z,yb1.w};
    float* yap = y_acc + rowA*HID + tA*8;
    float nxt[8];
    if (mode == 1){
      float a[8];
      #pragma unroll
      for (int i=0;i<8;++i){ a[i] = yb8[i] + (DT/6.f)*acc[i]; nxt[i] = yb8[i] + (0.5f*DT)*acc[i]; }
      *reinterpret_cast<float4*>(yap)   = make_float4(a[0],a[1],a[2],a[3]);
      *reinterpret_cast<float4*>(yap+4) = make_float4(a[4],a[5],a[6],a[7]);
    } else if (mode == 2 || mode == 3){
      float4 a0 = *reinterpret_cast<const float4*>(yap);
      float4 a1 = *reinterpret_cast<const float4*>(yap+4);
      float a[8] = {a0.x,a0.y,a0.z,a0.w,a1.x,a1.y,a1.z,a1.w};
      float cn = (mode==2) ? (0.5f*DT) : DT;
      #pragma unroll
      for (int i=0;i<8;++i){ a[i] += (DT/3.f)*acc[i]; nxt[i] = yb8[i] + cn*acc[i]; }
      *reinterpret_cast<float4*>(yap)   = make_float4(a[0],a[1],a[2],a[3]);
      *reinterpret_cast<float4*>(yap+4) = make_float4(a[4],a[5],a[6],a[7]);
    } else { // 4 or 5: y_new = y_acc + dt/6 * k4
      float4 a0 = *reinterpret_cast<const float4*>(yap);
      float4 a1 = *reinterpret_cast<const float4*>(yap+4);
      float a[8] = {a0.x,a0.y,a0.z,a0.w,a1.x,a1.y,a1.z,a1.w};
      #pragma unroll
      for (int i=0;i<8;++i) nxt[i] = a[i] + (DT/6.f)*acc[i];
      if (mode == 4){
        *reinterpret_cast<float4*>(y_base + rowA*HID + tA*8)   = make_float4(nxt[0],nxt[1],nxt[2],nxt[3]);
        *reinterpret_cast<float4*>(y_base + rowA*HID + tA*8+4) = make_float4(nxt[4],nxt[5],nxt[6],nxt[7]);
      }
    }
    #pragma unroll
    for (int i=0;i<8;++i) yt[rA*HID + tA*8 + i] = nxt[i];
  }

  // feature layout: fg = feature group (4 consecutive), rs = row slot (rows rs, rs+8)
  const int fg = tid & 31, rs = tid >> 5;
  const int rowF0 = row0 + rs, rowF1 = row0 + rs + 8;

  if (mode == 5){
    float z0[4], z1[4];
    if (seq_idx > 0){
      load_W(Wl, w_Wm, tid);
      __syncthreads();                      // yt(y_new) + w_W ready
      gemm128(Wl, yt, fg, rs, z0, z1);      // z = y_new @ w_W
      __syncthreads();                      // gemm reads done
      { // stage hin = inputs[:,idx] @ w_in + b_in into yt (layout A)
        float x0 = inputs[((bA*SEQL + seq_idx)*NNODE + nA)*2 + 0];
        float x1 = inputs[((bA*SEQL + seq_idx)*NNODE + nA)*2 + 1];
        #pragma unroll
        for (int i=0;i<8;++i){
          int f = tA*8 + i;
          yt[rA*HID + f] = x0*w_in[f] + x1*w_in[HID+f] + b_in[f];
        }
      }
      load_W(Wl, w_Um, tid);
      __syncthreads();
      float u0[4], u1[4];
      gemm128(Wl, yt, fg, rs, u0, u1);      // u = hin @ w_U
      #pragma unroll
      for (int i=0;i<4;++i){
        float bb = b_Wv[fg*4+i] + b_Uv[fg*4+i];
        z0[i] = tanhf(z0[i] + u0[i] + bb);
        z1[i] = tanhf(z1[i] + u1[i] + bb);
      }
    } else {
      __syncthreads();                      // yt(y_new) visible
      #pragma unroll
      for (int i=0;i<4;++i){
        z0[i] = yt[rs*HID + fg*4 + i];
        z1[i] = yt[(rs+8)*HID + fg*4 + i];
      }
    }
    // LayerNorm over 128 features (reduce across 32 fg lanes)
    float s0v=0.f,q0=0.f,s1v=0.f,q1=0.f;
    #pragma unroll
    for (int i=0;i<4;++i){ s0v+=z0[i]; q0+=z0[i]*z0[i]; s1v+=z1[i]; q1+=z1[i]*z1[i]; }
    #pragma unroll
    for (int off=1; off<32; off<<=1){
      s0v += __shfl_xor(s0v, off); q0 += __shfl_xor(q0, off);
      s1v += __shfl_xor(s1v, off); q1 += __shfl_xor(q1, off);
    }
    float mu0 = s0v*(1.f/HID), mu1 = s1v*(1.f/HID);
    float r0 = rsqrtf(q0*(1.f/HID) - mu0*mu0 + 1e-5f);
    float r1 = rsqrtf(q1*(1.f/HID) - mu1*mu1 + 1e-5f);
    #pragma unroll
    for (int i=0;i<4;++i){ z0[i] = (z0[i]-mu0)*r0; z1[i] = (z1[i]-mu1)*r1; }
    *reinterpret_cast<float4*>(y_base + rowF0*HID + fg*4) = make_float4(z0[0],z0[1],z0[2],z0[3]);
    *reinterpret_cast<float4*>(y_base + rowF1*HID + fg*4) = make_float4(z1[0],z1[1],z1[2],z1[3]);
    if (!write_h) return;                   // very last eval: out_kernel reads y_base
    __syncthreads();                        // all yt readers done
    *reinterpret_cast<float4*>(yt + rs*HID + fg*4)     = make_float4(z0[0],z0[1],z0[2],z0[3]);
    *reinterpret_cast<float4*>(yt + (rs+8)*HID + fg*4) = make_float4(z1[0],z1[1],z1[2],z1[3]);
    load_W(Wl, w_gat, tid);
    __syncthreads();
  } else {
    load_W(Wl, w_gat, tid);
    __syncthreads();
  }

  // ---- Phase D: h = next_in @ w_gat ; el/er epilogue ----
  float o0[4], o1[4];
  gemm128(Wl, yt, fg, rs, o0, o1);
  *reinterpret_cast<float4*>(h_wr + rowF0*HID + fg*4) = make_float4(o0[0],o0[1],o0[2],o0[3]);
  *reinterpret_cast<float4*>(h_wr + rowF1*HID + fg*4) = make_float4(o1[0],o1[1],o1[2],o1[3]);
  const int hd2 = fg >> 2, db = (fg & 3)*4;
  float elA=0.f, erA=0.f, elB=0.f, erB=0.f;
  #pragma unroll
  for (int i=0;i<4;++i){
    float alv = a_l[hd2*DHEAD + db + i];
    float arv = a_r[hd2*DHEAD + db + i];
    elA = fmaf(o0[i], alv, elA); erA = fmaf(o0[i], arv, erA);
    elB = fmaf(o1[i], alv, elB); erB = fmaf(o1[i], arv, erB);
  }
  elA += __shfl_xor(elA,1); elA += __shfl_xor(elA,2);
  erA += __shfl_xor(erA,1); erA += __shfl_xor(erA,2);
  elB += __shfl_xor(elB,1); elB += __shfl_xor(elB,2);
  erB += __shfl_xor(erB,1); erB += __shfl_xor(erB,2);
  if ((fg & 3) == 0){
    el_wr[rowF0*NHEAD + hd2] = elA; er_wr[rowF0*NHEAD + hd2] = erA;
    el_wr[rowF1*NHEAD + hd2] = elB; er_wr[rowF1*NHEAD + hd2] = erB;
  }
}

// out = tanh(ret @ w_o1 + b_o1) @ w_o2 + b_o2, fp32 output
__global__ void __launch_bounds__(256, 2) out_kernel(
    const float* __restrict__ y_base,
    const float* __restrict__ w_o1, const float* __restrict__ b_o1,
    const float* __restrict__ w_o2, const float* __restrict__ b_o2,
    float* __restrict__ out)
{
  __shared__ float Wl[HID*HID];
  __shared__ float yt[RPB*HID];
  const int tid = threadIdx.x;
  const int row0 = blockIdx.x * RPB;
  const int rA = tid >> 4, tA = tid & 15;
  const int rowA = row0 + rA;
  {
    float4 v0 = *reinterpret_cast<const float4*>(y_base + rowA*HID + tA*8);
    float4 v1 = *reinterpret_cast<const float4*>(y_base + rowA*HID + tA*8 + 4);
    *reinterpret_cast<float4*>(yt + rA*HID + tA*8)     = v0;
    *reinterpret_cast<float4*>(yt + rA*HID + tA*8 + 4) = v1;
  }
  load_W(Wl, w_o1, tid);
  __syncthreads();
  const int fg = tid & 31, rs = tid >> 5;
  float t0[4], t1[4];
  gemm128(Wl, yt, fg, rs, t0, t1);
  #pragma unroll
  for (int i=0;i<4;++i){
    float bb = b_o1[fg*4+i];
    t0[i] = tanhf(t0[i] + bb);
    t1[i] = tanhf(t1[i] + bb);
  }
  __syncthreads();
  *reinterpret_cast<float4*>(yt + rs*HID + fg*4)     = make_float4(t0[0],t0[1],t0[2],t0[3]);
  *reinterpret_cast<float4*>(yt + (rs+8)*HID + fg*4) = make_float4(t1[0],t1[1],t1[2],t1[3]);
  load_W(Wl, w_o2, tid);
  __syncthreads();
  float o0[4], o1[4];
  gemm128(Wl, yt, fg, rs, o0, o1);
  const int rowF0 = row0 + rs, rowF1 = row0 + rs + 8;
  *reinterpret_cast<float4*>(out + rowF0*HID + fg*4) =
      make_float4(o0[0]+b_o2[fg*4+0], o0[1]+b_o2[fg*4+1], o0[2]+b_o2[fg*4+2], o0[3]+b_o2[fg*4+3]);
  *reinterpret_cast<float4*>(out + rowF1*HID + fg*4) =
      make_float4(o1[0]+b_o2[fg*4+0], o1[1]+b_o2[fg*4+1], o1[2]+b_o2[fg*4+2], o1[3]+b_o2[fg*4+3]);
}

extern "C" void kernel_launch(void* const* d_in, const int* in_sizes, int n_in,
                              void* d_out, int out_size, void* d_ws, size_t ws_size,
                              hipStream_t stream)
{
  const float* inputs = (const float*)d_in[0];
  const int* src      = (const int*)d_in[1];
  const int* dst      = (const int*)d_in[2];
  const float* w_in   = (const float*)d_in[3];
  const float* b_in   = (const float*)d_in[4];
  const float* w_gat  = (const float*)d_in[5];
  const float* a_l    = (const float*)d_in[6];
  const float* a_r    = (const float*)d_in[7];
  const float* w_W    = (const float*)d_in[8];
  const float* b_W    = (const float*)d_in[9];
  const float* w_U    = (const float*)d_in[10];
  const float* b_U    = (const float*)d_in[11];
  const float* w_o1   = (const float*)d_in[12];
  const float* b_o1   = (const float*)d_in[13];
  const float* w_o2   = (const float*)d_in[14];
  const float* b_o2   = (const float*)d_in[15];

  float* F = reinterpret_cast<float*>(d_ws);
  const size_t RH = (size_t)NROWS * HID;    // 1,024,000
  const size_t RE = (size_t)NROWS * NHEAD;  // 64,000
  size_t need = (4*RH + 4*RE)*sizeof(float) + (size_t)(1024 + NEDGE)*sizeof(int);
  if (ws_size < need) return;

  float* y_base = F;
  float* y_acc  = F + RH;
  float* hb[2]  = { F + 2*RH, F + 3*RH };
  float* eb     = F + 4*RH;
  float* elb[2] = { eb, eb + RE };
  float* erb[2] = { eb + 2*RE, eb + 3*RE };
  int* I = reinterpret_cast<int*>(eb + 4*RE);
  int* row_start = I;
  int* edge_src  = I + 1024;

  csr_kernel<<<1, 1024, 0, stream>>>(src, dst, row_start, edge_src);

  // init: y0 = inputs[:,0]@w_in+b_in -> y_base; h/el/er buffer 0
  fused_eval<<<NBLK, 256, 0, stream>>>(
      hb[0], elb[0], erb[0], hb[0], elb[0], erb[0],
      y_base, y_acc, row_start, edge_src,
      w_gat, a_l, a_r, inputs, w_in, b_in, w_W, b_W, w_U, b_U,
      0, 0, 1);

  int rd = 0;
  for (int idx = 0; idx < SEQL; ++idx){
    for (int st = 0; st < 4; ++st){
      for (int j = 1; j <= 4; ++j){
        int mode = (j < 4) ? j : ((st < 3) ? 4 : 5);
        int wr = 1 - rd;
        int last = (idx == SEQL-1 && st == 3 && j == 4) ? 1 : 0;
        fused_eval<<<NBLK, 256, 0, stream>>>(
            hb[rd], elb[rd], erb[rd], hb[wr], elb[wr], erb[wr],
            y_base, y_acc, row_start, edge_src,
            w_gat, a_l, a_r, inputs, w_in, b_in, w_W, b_W, w_U, b_U,
            mode, idx, last ? 0 : 1);
        rd = wr;
      }
    }
  }

  out_kernel<<<NBLK, 256, 0, stream>>>(y_base, w_o1, b_o1, w_o2, b_o2, (float*)d_out);
}